// Round 2
// baseline (153.369 us; speedup 1.0000x reference)
//
#include <hip/hip_runtime.h>
#include <stdint.h>

// Soft-DTW forward, B=64, N=M=512, gamma=1, no band.
// 64 blocks (1/batch) x 4 waves. Lane l of wave w owns DP rows 128w+2l+1/+2.
// Skewed wavefront: at wave-local step t, lane computes column c = t - l for
// both rows (2 serial softmin cells). Intra-wave row handoff via DPP
// wave_shr:1 on x2; inter-wave handoff via bnd[] LDS with final-write-wins
// (all lanes store; lane 63 provably writes last) and 2-barrier slack.
// D fetched with bounds-checked buffer_load_dwordx4 at unaligned per-lane
// offsets so step s -> compile-time register component (zero VALU extract).

namespace {
constexpr int NWAVE = 4;
constexpr int DELTA = 96;                         // wave-to-wave step offset
constexpr int MCOLS = 512;
constexpr int LOCAL = MCOLS + 63;                 // 575 steps per wave
constexpr int TOTAL = (NWAVE - 1) * DELTA + LOCAL;  // 863
constexpr int NCHUNK = (((TOTAL + 15) / 16) + 1) & ~1;  // 54 (even)
constexpr int BROW = 608;                         // 513 live + 64 trash + pad
constexpr float INFV = 1e30f;
constexpr float L2E = 1.44269504088896340736f;    // log2(e)
constexpr float LN2 = 0.69314718055994530942f;
}

using f4 = __attribute__((ext_vector_type(4))) float;
using u32x4 = __attribute__((ext_vector_type(4))) unsigned int;

__device__ __forceinline__ float dpp_shr1(float v) {
    // lane n <- lane n-1 (wave_shr:1 = 0x138); lane 0 overridden by isL0 select
    return __int_as_float(
        __builtin_amdgcn_update_dpp(0, __float_as_int(v), 0x138, 0xf, 0xf, true));
}
__device__ __forceinline__ float rdlane(float v, int lane) {
    return __int_as_float(__builtin_amdgcn_readlane(__float_as_int(v), lane));
}
// All DP values carry a x log2(e) scale: softmin3 = mn - log2(sum exp2(mn-v)).
// exp2(mn-mn)=1 is folded; mx/md via single-instr max3/med3.
__device__ __forceinline__ float softmin3(float a, float b, float c) {
    float mn = fminf(fminf(a, b), c);
    float mx = fmaxf(fmaxf(a, b), c);
    float md = __builtin_amdgcn_fmed3f(a, b, c);
    float sum = 1.0f + __builtin_amdgcn_exp2f(mn - md) + __builtin_amdgcn_exp2f(mn - mx);
    return mn - __builtin_amdgcn_logf(sum);
}

// 16 DP steps over the current chunk. G = guarded (fill/drain) variant.
template <bool G>
__device__ __forceinline__ void steps16(
    f4 (&q)[7], float e0, float e1, float e2, float e3,
    int t0, int l, int w, int b, bool isL0, float a0v, float curv,
    float (&bnd)[NWAVE][BROW], float* __restrict__ out,
    float& x1, float& x2, float& areg)
{
#pragma unroll
    for (int s = 0; s < 16; ++s) {
        const int c = t0 + s - l;
        const float d1 = q[s >> 2][s & 3];
        const float d2 = (s < 12) ? q[4 + (s >> 2)][s & 3]
                                  : (s == 12 ? e0 : s == 13 ? e1 : s == 14 ? e2 : e3);
        const float bsh = dpp_shr1(x2);                 // up-row val from lane l-1
        const float bb = isL0 ? rdlane(curv, s) : bsh;  // lane0: wave-boundary
        float aa, xo;
        if (G) {
            const bool is0 = (c == 0);
            aa = is0 ? a0v : areg;
            xo = is0 ? INFV : x1;
        } else {
            aa = areg;
            xo = x1;
        }
        // row i1: inputs (R[i1-1][c], R[i1-1][c+1], R[i1][c])
        const float x1n = fmaf(d1, L2E, softmin3(aa, bb, xo));
        // row i2: inputs (R[i1][c] = old x1, R[i1][c+1] = x1n, R[i2][c] = x2)
        const float x2n = fmaf(d2, L2E, softmin3(x1, x1n, x2));
        if (G) {
            const bool act = (unsigned)c < 512u;
            const int colc = act ? c : (513 + (c & 63));  // trash for OOB cols
            bnd[w][colc] = x2n;
            x1 = act ? x1n : x1;
            x2 = act ? x2n : x2;
            if (w == NWAVE - 1 && l == 63 && c == MCOLS - 1) out[b] = x2n * LN2;
        } else {
            bnd[w][c] = x2n;  // all lanes store; lane63 (t=c+63) writes last
            x1 = x1n;
            x2 = x2n;
        }
        areg = bsh;
    }
}

// Issue the 11 loads for the chunk starting at wave-local step T0N.
// Rows r1 (4x dwordx4) and r1+1 (3x dwordx4 + 4x dword: the scalar tail keeps
// the absolute-last-row quad from tripping the whole-access bounds check).
#define ISSUE(Q, E0, E1, E2, E3, T0N) do {                                          \
    const int st_ = (T0N) - l;                                                      \
    const int vo1_ = byte1 + (st_ << 2);                                            \
    const int vo2_ = vo1_ + 2048;                                                   \
    asm volatile("buffer_load_dwordx4 %0, %1, %2, 0 offen"           : "=v"(Q[0]) : "v"(vo1_), "s"(srd)); \
    asm volatile("buffer_load_dwordx4 %0, %1, %2, 0 offen offset:16" : "=v"(Q[1]) : "v"(vo1_), "s"(srd)); \
    asm volatile("buffer_load_dwordx4 %0, %1, %2, 0 offen offset:32" : "=v"(Q[2]) : "v"(vo1_), "s"(srd)); \
    asm volatile("buffer_load_dwordx4 %0, %1, %2, 0 offen offset:48" : "=v"(Q[3]) : "v"(vo1_), "s"(srd)); \
    asm volatile("buffer_load_dwordx4 %0, %1, %2, 0 offen"           : "=v"(Q[4]) : "v"(vo2_), "s"(srd)); \
    asm volatile("buffer_load_dwordx4 %0, %1, %2, 0 offen offset:16" : "=v"(Q[5]) : "v"(vo2_), "s"(srd)); \
    asm volatile("buffer_load_dwordx4 %0, %1, %2, 0 offen offset:32" : "=v"(Q[6]) : "v"(vo2_), "s"(srd)); \
    asm volatile("buffer_load_dword   %0, %1, %2, 0 offen offset:48" : "=v"(E0)  : "v"(vo2_), "s"(srd)); \
    asm volatile("buffer_load_dword   %0, %1, %2, 0 offen offset:52" : "=v"(E1)  : "v"(vo2_), "s"(srd)); \
    asm volatile("buffer_load_dword   %0, %1, %2, 0 offen offset:56" : "=v"(E2)  : "v"(vo2_), "s"(srd)); \
    asm volatile("buffer_load_dword   %0, %1, %2, 0 offen offset:60" : "=v"(E3)  : "v"(vo2_), "s"(srd)); \
} while (0)

// Wait for the current chunk's 11 loads (leave the 11 just-issued in flight).
// "+v" ties make the data dependence explicit -> cannot be hoisted past.
#define WAITQ(Q, E0, E1, E2, E3)                                                    \
    asm volatile("s_waitcnt vmcnt(11)"                                              \
        : "+v"(Q[0]), "+v"(Q[1]), "+v"(Q[2]), "+v"(Q[3]), "+v"(Q[4]), "+v"(Q[5]),  \
          "+v"(Q[6]), "+v"(E0), "+v"(E1), "+v"(E2), "+v"(E3)::)

#define BODY(CQ, CE0, CE1, CE2, CE3, NQ, NE0, NE1, NE2, NE3, MC) do {               \
    const int t0_ = 16 * (MC) - ow;                                                 \
    ISSUE(NQ, NE0, NE1, NE2, NE3, 16 * ((MC) + 1) - ow);                            \
    WAITQ(CQ, CE0, CE1, CE2, CE3);                                                  \
    if (t0_ >= 0 && t0_ < LOCAL) {                                                  \
        float curv = INFV;                                                          \
        if (w > 0 && t0_ < 512) curv = bnd[w - 1][t0_ + (l & 15)];                  \
        if (t0_ >= 64 && t0_ <= 496)                                                \
            steps16<false>(CQ, CE0, CE1, CE2, CE3, t0_, l, w, b, isL0, a0v, curv,   \
                           bnd, out, x1, x2, areg);                                 \
        else                                                                        \
            steps16<true>(CQ, CE0, CE1, CE2, CE3, t0_, l, w, b, isL0, a0v, curv,    \
                          bnd, out, x1, x2, areg);                                  \
    }                                                                               \
    __syncthreads();                                                                \
} while (0)

__global__ __launch_bounds__(256, 1) void sdtw_kernel(const float* __restrict__ D,
                                                      float* __restrict__ out) {
    static_assert(NCHUNK % 2 == 0, "loop is 2x unrolled");
    __shared__ float bnd[NWAVE][BROW];
    const int tid = threadIdx.x;
    const int w = tid >> 6, l = tid & 63, b = blockIdx.x;

    u32x4 srd;  // raw buffer descriptor over D: OOB reads return 0, never fault
    const uint64_t base = (uint64_t)(const void*)D;
    srd[0] = (unsigned)base;
    srd[1] = (unsigned)(base >> 32) & 0xffffu;  // stride=0
    srd[2] = 64u * 512u * 512u * 4u;            // num_records (bytes)
    srd[3] = 0x00020000u;

    const int r1 = (w << 7) + (l << 1);        // D row of i1 (0-based)
    const int byte1 = ((b << 9) + r1) << 11;   // (b*512 + r1) * 512 * 4
    const int ow = w * DELTA;
    const bool isL0 = (l == 0);
    const float a0v = (tid == 0) ? 0.0f : INFV;  // R[0][0]=0 only for cell (1,1)

    float x1 = INFV, x2 = INFV, areg = INFV;
    f4 qa[7], qb[7];
    float ea0, ea1, ea2, ea3, eb0, eb1, eb2, eb3;

    ISSUE(qa, ea0, ea1, ea2, ea3, -ow);  // chunk 0
    for (int mc = 0; mc < NCHUNK; mc += 2) {
        BODY(qa, ea0, ea1, ea2, ea3, qb, eb0, eb1, eb2, eb3, mc);
        BODY(qb, eb0, eb1, eb2, eb3, qa, ea0, ea1, ea2, ea3, mc + 1);
    }
}

extern "C" void kernel_launch(void* const* d_in, const int* in_sizes, int n_in,
                              void* d_out, int out_size, void* d_ws, size_t ws_size,
                              hipStream_t stream) {
    const float* D = (const float*)d_in[0];
    float* out = (float*)d_out;
    hipLaunchKernelGGL(sdtw_kernel, dim3(64), dim3(256), 0, stream, D, out);
}

// Round 6
// 115.715 us; speedup vs baseline: 1.3254x; 1.3254x over previous
//
#include <hip/hip_runtime.h>
#include <stdint.h>
#include <math.h>

// Soft-DTW forward, B=64, N=M=512, gamma=1 — probability-domain wavefront DP
// on the round-2 proven skeleton (CHUNK=16, DELTA=96, tied-vmcnt, syncthreads).
// R = d + softmin(a,b,c) carried as P = exp(-R): P_new = exp(-d)*(Pa+Pb+Pc)
// -> critical chain is dpp -> mul(rsc) -> cndmask -> fma -> fma.
// Scale: PER-LANE exponent E (P_true = x * 2^E). Per-chunk renorm recenters
// each lane's max(x1,x2) exponent to 2^-10 (drift within a chunk is bounded
// by 2^51 up / 2^-23 down -> no over/underflow). Lane->lane DPP handoff is
// rescaled by rsc = 2^(E_{l-1}-E_l), exact because inactive lanes adopt their
// left neighbor's E every chunk (|dE| stays small). Inter-wave handoff
// reconciles exactly via v_ldexp_f32 against lane-63-published per-chunk E.
//
// 64 blocks (1/batch) x 4 waves. Lane l of wave w owns DP rows 128w+2l+1/+2.
// At wave-local step t, lane computes column c = t-l for both rows.

namespace {
constexpr int NWAVE = 4;
constexpr int DELTA = 96;                     // wave-to-wave step offset
constexpr int MCOLS = 512;
constexpr int LOCAL = MCOLS + 63;             // 575 steps per wave
constexpr int NCHUNK = 54;                    // 54*16=864 >= 3*96+575=863, even
constexpr int BROW = 608;                     // live 0..511, trash 544..607
constexpr float LN2 = 0.69314718055994530942f;
constexpr float L2E = 1.44269504088896340736f;
}

using f4 = __attribute__((ext_vector_type(4))) float;
using u32x4 = __attribute__((ext_vector_type(4))) unsigned int;

__device__ __forceinline__ float dpp_shr1(float v) {
  // lane n <- lane n-1 (wave_shr:1); lane 0 reads 0 (bound_ctrl) = P(INF)
  return __int_as_float(__builtin_amdgcn_update_dpp(0, __float_as_int(v), 0x138, 0xf, 0xf, true));
}
__device__ __forceinline__ int dpp_shr1_i(int v) {
  return __builtin_amdgcn_update_dpp(0, v, 0x138, 0xf, 0xf, true);
}
__device__ __forceinline__ float rdlane(float v, int lane) {
  return __int_as_float(__builtin_amdgcn_readlane(__float_as_int(v), lane));
}

// 16 DP steps over the current chunk. G = guarded (fill/drain) variant.
template <bool G>
__device__ __forceinline__ void steps16(
    f4 (&q)[7], float e0, float e1, float e2, float e3,
    int t0, int l, int tid, bool isL0, float rsc, float curv,
    float* __restrict__ bwr,
    float& x1, float& x2, float& areg)
{
#pragma unroll
  for (int s = 0; s < 16; ++s) {
    const int c = t0 + s - l;
    const float d1 = q[s >> 2][s & 3];
    const float d2 = (s < 12) ? q[4 + (s >> 2)][s & 3]
                              : (s == 12 ? e0 : s == 13 ? e1 : s == 14 ? e2 : e3);
    // off-chain: exp(-d) = exp2(-d*log2e), inputs prefetched a chunk ahead
    const float k1 = __builtin_amdgcn_exp2f(d1 * -L2E);
    const float k2 = __builtin_amdgcn_exp2f(d2 * -L2E);
    float aa = areg;
    if (G) aa = (tid == 0 && c == 0) ? 1.0f : aa;  // P(R[0][0]=0)=1 seed
    const float k1s1 = k1 * (aa + x1);  // off-chain
    const float k2s2 = k2 * (x1 + x2);  // off-chain
    // chain: dpp -> mul -> cndmask -> fma -> fma
    const float bsh = dpp_shr1(x2) * rsc;           // lane l-1's x2, rescaled
    const float bb = isL0 ? rdlane(curv, s) : bsh;  // lane0: wave-boundary
    const float x1n = fmaf(k1, bb, k1s1);   // row i1: k1*(aa+x1+bb)
    const float x2n = fmaf(k2, x1n, k2s2);  // row i2: k2*(x1+x2+x1n)
    if (G) {
      const bool act = (unsigned)c < 512u;
      const int idx = act ? c : (int)(544u + ((unsigned)c & 63u));  // OOB->trash
      bwr[idx] = x2n;
      x1 = act ? x1n : x1;
      x2 = act ? x2n : x2;
    } else {
      bwr[c] = x2n;  // all lanes store; lane 63 (step c+63) writes last
      x1 = x1n;
      x2 = x2n;
    }
    areg = bb;  // next step's diagonal (incl. lane-0 boundary value)
  }
}

// Issue the 11 loads for the chunk starting at wave-local step T0N.
// Rows r1 (4x dwordx4) and r1+1 (3x dwordx4 + 4x dword: the scalar tail keeps
// the absolute-last-row quad from tripping the whole-access bounds check).
#define ISSUE(Q, E0, E1, E2, E3, T0N) do {                                          \
    const int st_ = (T0N) - l;                                                      \
    const int vo1_ = byte1 + (st_ << 2);                                            \
    const int vo2_ = vo1_ + 2048;                                                   \
    asm volatile("buffer_load_dwordx4 %0, %1, %2, 0 offen"           : "=v"(Q[0]) : "v"(vo1_), "s"(srd)); \
    asm volatile("buffer_load_dwordx4 %0, %1, %2, 0 offen offset:16" : "=v"(Q[1]) : "v"(vo1_), "s"(srd)); \
    asm volatile("buffer_load_dwordx4 %0, %1, %2, 0 offen offset:32" : "=v"(Q[2]) : "v"(vo1_), "s"(srd)); \
    asm volatile("buffer_load_dwordx4 %0, %1, %2, 0 offen offset:48" : "=v"(Q[3]) : "v"(vo1_), "s"(srd)); \
    asm volatile("buffer_load_dwordx4 %0, %1, %2, 0 offen"           : "=v"(Q[4]) : "v"(vo2_), "s"(srd)); \
    asm volatile("buffer_load_dwordx4 %0, %1, %2, 0 offen offset:16" : "=v"(Q[5]) : "v"(vo2_), "s"(srd)); \
    asm volatile("buffer_load_dwordx4 %0, %1, %2, 0 offen offset:32" : "=v"(Q[6]) : "v"(vo2_), "s"(srd)); \
    asm volatile("buffer_load_dword   %0, %1, %2, 0 offen offset:48" : "=v"(E0)  : "v"(vo2_), "s"(srd)); \
    asm volatile("buffer_load_dword   %0, %1, %2, 0 offen offset:52" : "=v"(E1)  : "v"(vo2_), "s"(srd)); \
    asm volatile("buffer_load_dword   %0, %1, %2, 0 offen offset:56" : "=v"(E2)  : "v"(vo2_), "s"(srd)); \
    asm volatile("buffer_load_dword   %0, %1, %2, 0 offen offset:60" : "=v"(E3)  : "v"(vo2_), "s"(srd)); \
} while (0)

// Wait for the current chunk's 11 loads (leave the 11 just-issued in flight).
// "+v" ties make the data dependence explicit -> consumers cannot hoist.
#define WAITQ(Q, E0, E1, E2, E3)                                                    \
    asm volatile("s_waitcnt vmcnt(11)"                                              \
        : "+v"(Q[0]), "+v"(Q[1]), "+v"(Q[2]), "+v"(Q[3]), "+v"(Q[4]), "+v"(Q[5]),  \
          "+v"(Q[6]), "+v"(E0), "+v"(E1), "+v"(E2), "+v"(E3)::)

#define BODY(CQ, CE0, CE1, CE2, CE3, NQ, NE0, NE1, NE2, NE3, MC) do {               \
    const int t0_ = 16 * (MC) - ow;                                                 \
    ISSUE(NQ, NE0, NE1, NE2, NE3, 16 * ((MC) + 1) - ow);                            \
    WAITQ(CQ, CE0, CE1, CE2, CE3);                                                  \
    if (t0_ >= 0 && t0_ < LOCAL) {                                                  \
      /* per-lane scale maintenance */                                              \
      const int ENpre_ = dpp_shr1_i(E);                                             \
      const bool inact_ = (x1 == 0.0f) && (x2 == 0.0f);                             \
      if (w > 0 && t0_ == 0) E = brdE[3];        /* whole-wave scale adoption */    \
      else if (inact_ && !isL0) E = ENpre_;      /* track left neighbor */          \
      float curv_ = 0.0f;                                                           \
      if (w > 0 && t0_ < 512) {                                                     \
        const int j_ = l & 15;                                                      \
        /* column t0+j finalized during writer chunk k+3 (j==0) or k+4 (j>0) */     \
        const int Eb_ = brdE[(t0_ >> 4) + (j_ ? 4 : 3)];                            \
        const int E0_ = __builtin_amdgcn_readfirstlane(E);                          \
        curv_ = ldexpf(brd[t0_ + j_], Eb_ - E0_);  /* exact reconcile, lane-0 scale */ \
      }                                                                             \
      if (l == 63) bwrE[t0_ >> 4] = E;           /* lane 63 makes final writes */   \
      const int EN2_ = dpp_shr1_i(E);                                               \
      int dE_ = EN2_ - E;                                                           \
      dE_ = dE_ < -126 ? -126 : (dE_ > 126 ? 126 : dE_);                            \
      const float rsc_ = __int_as_float((127 + dE_) << 23);                         \
      if (t0_ >= 64 && t0_ <= 496)                                                  \
        steps16<false>(CQ, CE0, CE1, CE2, CE3, t0_, l, tid, isL0, rsc_, curv_, bwr, \
                       x1, x2, areg);                                               \
      else                                                                          \
        steps16<true>(CQ, CE0, CE1, CE2, CE3, t0_, l, tid, isL0, rsc_, curv_, bwr,  \
                      x1, x2, areg);                                                \
      /* per-lane renorm: recenter max(x1,x2) exponent to 2^-10 */                  \
      const int bx_ = (__float_as_int(x1) >> 23) & 255;                             \
      const int by_ = (__float_as_int(x2) >> 23) & 255;                             \
      int exm_ = bx_ > by_ ? bx_ : by_;                                             \
      int sh_ = (exm_ > 0) ? (117 - exm_) : 0;                                      \
      sh_ = sh_ < -110 ? -110 : sh_;                                                \
      const float sc_ = __int_as_float((127 + sh_) << 23);                          \
      x1 *= sc_; x2 *= sc_; areg *= sc_; E -= sh_;                                  \
    }                                                                               \
    __syncthreads();                                                                \
} while (0)

__global__ __launch_bounds__(256, 1) void sdtw_kernel(const float* __restrict__ D,
                                                      float* __restrict__ out) {
  static_assert(NCHUNK % 2 == 0, "loop is 2x unrolled");
  __shared__ float bnd[NWAVE + 1][BROW];  // [4] = dump row for wave 3
  __shared__ int bndE[NWAVE][36];         // per-wave per-chunk lane-63 scale E
  const int tid = threadIdx.x;
  const int w = tid >> 6, l = tid & 63, b = blockIdx.x;

  u32x4 srd;  // raw buffer descriptor over D: OOB reads return 0, never fault
  const uint64_t base = (uint64_t)(const void*)D;
  srd[0] = (unsigned)base;
  srd[1] = (unsigned)(base >> 32) & 0xffffu;  // stride=0
  srd[2] = 64u * 512u * 512u * 4u;            // num_records (bytes)
  srd[3] = 0x00020000u;

  const int r1 = (w << 7) + (l << 1);       // D row of i1 (0-based)
  const int byte1 = ((b << 9) + r1) << 11;  // (b*512 + r1) * 512 * 4
  const int ow = w * DELTA;
  const bool isL0 = (l == 0);

  float* __restrict__ bwr = &bnd[(w == NWAVE - 1) ? NWAVE : w][0];
  float* __restrict__ brd = &bnd[(w == 0) ? 0 : (w - 1)][0];
  int* __restrict__ bwrE = &bndE[w][0];
  int* __restrict__ brdE = &bndE[(w == 0) ? 0 : (w - 1)][0];

  float x1 = 0.0f, x2 = 0.0f, areg = 0.0f;  // P(INF) = 0
  int E = 0;                                // per-lane scale exponent

  f4 qa[7], qb[7];
  float ea0, ea1, ea2, ea3, eb0, eb1, eb2, eb3;

  ISSUE(qa, ea0, ea1, ea2, ea3, -ow);  // chunk 0
  for (int mc = 0; mc < NCHUNK; mc += 2) {
    BODY(qa, ea0, ea1, ea2, ea3, qb, eb0, eb1, eb2, eb3, mc);
    BODY(qb, eb0, eb1, eb2, eb3, qa, ea0, ea1, ea2, ea3, mc + 1);
  }

  if (tid == NWAVE * 64 - 1) {
    // x2 * 2^E = exp(-R[512][512]);  v_log_f32 is log2
    const float Rv = -(__builtin_amdgcn_logf(x2) + (float)E);
    out[b] = Rv * LN2;
  }
}

extern "C" void kernel_launch(void* const* d_in, const int* in_sizes, int n_in,
                              void* d_out, int out_size, void* d_ws, size_t ws_size,
                              hipStream_t stream) {
  const float* D = (const float*)d_in[0];
  float* out = (float*)d_out;
  hipLaunchKernelGGL(sdtw_kernel, dim3(64), dim3(NWAVE * 64), 0, stream, D, out);
}

// Round 7
// 115.631 us; speedup vs baseline: 1.3264x; 1.0007x over previous
//
#include <hip/hip_runtime.h>
#include <stdint.h>
#include <math.h>

// Soft-DTW forward, B=64, N=M=512, gamma=1 — probability-domain wavefront DP
// on the round-2 proven skeleton (CHUNK=16, DELTA=96, tied-vmcnt, syncthreads).
// R = d + softmin(a,b,c) carried as P = exp(-R): P_new = exp(-d)*(Pa+Pb+Pc)
// -> critical chain is dpp -> mul(rsc) -> cndmask -> fma -> fma.
// Scale: PER-LANE exponent E (P_true = x * 2^E), per-chunk renorm to 2^-10;
// lane->lane DPP handoff rescaled by rsc = 2^(E_{l-1}-E_l); inter-wave
// handoff reconciled exactly via v_ldexp_f32 + lane-63-published per-chunk E.
//
// ROUND 7 DELTA (only change vs round 6): D prefetch buffers are 14 NAMED f4
// variables instead of f4[7] arrays — the array form was lowered to scratch
// (VGPR_Count=44 < the 56 regs the buffers need), putting ~150-300cy scratch
// round-trips on the wavefront critical path every chunk.
//
// 64 blocks (1/batch) x 4 waves. Lane l of wave w owns DP rows 128w+2l+1/+2.
// At wave-local step t, lane computes column c = t-l for both rows.

namespace {
constexpr int NWAVE = 4;
constexpr int DELTA = 96;                     // wave-to-wave step offset
constexpr int MCOLS = 512;
constexpr int LOCAL = MCOLS + 63;             // 575 steps per wave
constexpr int NCHUNK = 54;                    // 54*16=864 >= 3*96+575=863, even
constexpr int BROW = 608;                     // live 0..511, trash 544..607
constexpr float LN2 = 0.69314718055994530942f;
constexpr float L2E = 1.44269504088896340736f;
}

using f4 = __attribute__((ext_vector_type(4))) float;
using u32x4 = __attribute__((ext_vector_type(4))) unsigned int;

__device__ __forceinline__ float dpp_shr1(float v) {
  // lane n <- lane n-1 (wave_shr:1); lane 0 reads 0 (bound_ctrl) = P(INF)
  return __int_as_float(__builtin_amdgcn_update_dpp(0, __float_as_int(v), 0x138, 0xf, 0xf, true));
}
__device__ __forceinline__ int dpp_shr1_i(int v) {
  return __builtin_amdgcn_update_dpp(0, v, 0x138, 0xf, 0xf, true);
}
__device__ __forceinline__ float rdlane(float v, int lane) {
  return __int_as_float(__builtin_amdgcn_readlane(__float_as_int(v), lane));
}

// 16 DP steps over the current chunk. G = guarded (fill/drain) variant.
template <bool G>
__device__ __forceinline__ void steps16(
    const f4& q0, const f4& q1, const f4& q2, const f4& q3,
    const f4& q4, const f4& q5, const f4& q6,
    float e0, float e1, float e2, float e3,
    int t0, int l, int tid, bool isL0, float rsc, float curv,
    float* __restrict__ bwr,
    float& x1, float& x2, float& areg)
{
#pragma unroll
  for (int s = 0; s < 16; ++s) {
    const int c = t0 + s - l;
    const float d1 = (s < 4) ? q0[s & 3] : (s < 8) ? q1[s & 3]
                   : (s < 12) ? q2[s & 3] : q3[s & 3];
    const float d2 = (s < 4) ? q4[s & 3] : (s < 8) ? q5[s & 3]
                   : (s < 12) ? q6[s & 3]
                   : (s == 12 ? e0 : s == 13 ? e1 : s == 14 ? e2 : e3);
    // off-chain: exp(-d) = exp2(-d*log2e), inputs prefetched a chunk ahead
    const float k1 = __builtin_amdgcn_exp2f(d1 * -L2E);
    const float k2 = __builtin_amdgcn_exp2f(d2 * -L2E);
    float aa = areg;
    if (G) aa = (tid == 0 && c == 0) ? 1.0f : aa;  // P(R[0][0]=0)=1 seed
    const float k1s1 = k1 * (aa + x1);  // off-chain
    const float k2s2 = k2 * (x1 + x2);  // off-chain
    // chain: dpp -> mul -> cndmask -> fma -> fma
    const float bsh = dpp_shr1(x2) * rsc;           // lane l-1's x2, rescaled
    const float bb = isL0 ? rdlane(curv, s) : bsh;  // lane0: wave-boundary
    const float x1n = fmaf(k1, bb, k1s1);   // row i1: k1*(aa+x1+bb)
    const float x2n = fmaf(k2, x1n, k2s2);  // row i2: k2*(x1+x2+x1n)
    if (G) {
      const bool act = (unsigned)c < 512u;
      const int idx = act ? c : (int)(544u + ((unsigned)c & 63u));  // OOB->trash
      bwr[idx] = x2n;
      x1 = act ? x1n : x1;
      x2 = act ? x2n : x2;
    } else {
      bwr[c] = x2n;  // all lanes store; lane 63 (step c+63) writes last
      x1 = x1n;
      x2 = x2n;
    }
    areg = bb;  // next step's diagonal (incl. lane-0 boundary value)
  }
}

// Issue the 11 loads for the chunk starting at wave-local step T0N.
// Rows r1 (4x dwordx4) and r1+1 (3x dwordx4 + 4x dword: the scalar tail keeps
// the absolute-last-row quad from tripping the whole-access bounds check).
#define ISSUE(Q0, Q1, Q2, Q3, Q4, Q5, Q6, E0, E1, E2, E3, T0N) do {                 \
    const int st_ = (T0N) - l;                                                      \
    const int vo1_ = byte1 + (st_ << 2);                                            \
    const int vo2_ = vo1_ + 2048;                                                   \
    asm volatile("buffer_load_dwordx4 %0, %1, %2, 0 offen"           : "=v"(Q0) : "v"(vo1_), "s"(srd)); \
    asm volatile("buffer_load_dwordx4 %0, %1, %2, 0 offen offset:16" : "=v"(Q1) : "v"(vo1_), "s"(srd)); \
    asm volatile("buffer_load_dwordx4 %0, %1, %2, 0 offen offset:32" : "=v"(Q2) : "v"(vo1_), "s"(srd)); \
    asm volatile("buffer_load_dwordx4 %0, %1, %2, 0 offen offset:48" : "=v"(Q3) : "v"(vo1_), "s"(srd)); \
    asm volatile("buffer_load_dwordx4 %0, %1, %2, 0 offen"           : "=v"(Q4) : "v"(vo2_), "s"(srd)); \
    asm volatile("buffer_load_dwordx4 %0, %1, %2, 0 offen offset:16" : "=v"(Q5) : "v"(vo2_), "s"(srd)); \
    asm volatile("buffer_load_dwordx4 %0, %1, %2, 0 offen offset:32" : "=v"(Q6) : "v"(vo2_), "s"(srd)); \
    asm volatile("buffer_load_dword   %0, %1, %2, 0 offen offset:48" : "=v"(E0) : "v"(vo2_), "s"(srd)); \
    asm volatile("buffer_load_dword   %0, %1, %2, 0 offen offset:52" : "=v"(E1) : "v"(vo2_), "s"(srd)); \
    asm volatile("buffer_load_dword   %0, %1, %2, 0 offen offset:56" : "=v"(E2) : "v"(vo2_), "s"(srd)); \
    asm volatile("buffer_load_dword   %0, %1, %2, 0 offen offset:60" : "=v"(E3) : "v"(vo2_), "s"(srd)); \
} while (0)

// Wait for the current chunk's 11 loads (leave the 11 just-issued in flight).
// "+v" ties make the data dependence explicit -> consumers cannot hoist.
#define WAITQ(Q0, Q1, Q2, Q3, Q4, Q5, Q6, E0, E1, E2, E3)                           \
    asm volatile("s_waitcnt vmcnt(11)"                                              \
        : "+v"(Q0), "+v"(Q1), "+v"(Q2), "+v"(Q3), "+v"(Q4), "+v"(Q5),              \
          "+v"(Q6), "+v"(E0), "+v"(E1), "+v"(E2), "+v"(E3)::)

#define BODY(CQ0, CQ1, CQ2, CQ3, CQ4, CQ5, CQ6, CE0, CE1, CE2, CE3,                 \
             NQ0, NQ1, NQ2, NQ3, NQ4, NQ5, NQ6, NE0, NE1, NE2, NE3, MC) do {        \
    const int t0_ = 16 * (MC) - ow;                                                 \
    ISSUE(NQ0, NQ1, NQ2, NQ3, NQ4, NQ5, NQ6, NE0, NE1, NE2, NE3,                    \
          16 * ((MC) + 1) - ow);                                                    \
    WAITQ(CQ0, CQ1, CQ2, CQ3, CQ4, CQ5, CQ6, CE0, CE1, CE2, CE3);                   \
    if (t0_ >= 0 && t0_ < LOCAL) {                                                  \
      /* per-lane scale maintenance */                                              \
      const int ENpre_ = dpp_shr1_i(E);                                             \
      const bool inact_ = (x1 == 0.0f) && (x2 == 0.0f);                             \
      if (w > 0 && t0_ == 0) E = brdE[3];        /* whole-wave scale adoption */    \
      else if (inact_ && !isL0) E = ENpre_;      /* track left neighbor */          \
      float curv_ = 0.0f;                                                           \
      if (w > 0 && t0_ < 512) {                                                     \
        const int j_ = l & 15;                                                      \
        /* column t0+j finalized during writer chunk k+3 (j==0) or k+4 (j>0) */     \
        const int Eb_ = brdE[(t0_ >> 4) + (j_ ? 4 : 3)];                            \
        const int E0_ = __builtin_amdgcn_readfirstlane(E);                          \
        curv_ = ldexpf(brd[t0_ + j_], Eb_ - E0_);  /* exact reconcile, lane-0 scale */ \
      }                                                                             \
      if (l == 63) bwrE[t0_ >> 4] = E;           /* lane 63 makes final writes */   \
      const int EN2_ = dpp_shr1_i(E);                                               \
      int dE_ = EN2_ - E;                                                           \
      dE_ = dE_ < -126 ? -126 : (dE_ > 126 ? 126 : dE_);                            \
      const float rsc_ = __int_as_float((127 + dE_) << 23);                         \
      if (t0_ >= 64 && t0_ <= 496)                                                  \
        steps16<false>(CQ0, CQ1, CQ2, CQ3, CQ4, CQ5, CQ6, CE0, CE1, CE2, CE3,       \
                       t0_, l, tid, isL0, rsc_, curv_, bwr, x1, x2, areg);           \
      else                                                                          \
        steps16<true>(CQ0, CQ1, CQ2, CQ3, CQ4, CQ5, CQ6, CE0, CE1, CE2, CE3,        \
                      t0_, l, tid, isL0, rsc_, curv_, bwr, x1, x2, areg);            \
      /* per-lane renorm: recenter max(x1,x2) exponent to 2^-10 */                  \
      const int bx_ = (__float_as_int(x1) >> 23) & 255;                             \
      const int by_ = (__float_as_int(x2) >> 23) & 255;                             \
      int exm_ = bx_ > by_ ? bx_ : by_;                                             \
      int sh_ = (exm_ > 0) ? (117 - exm_) : 0;                                      \
      sh_ = sh_ < -110 ? -110 : sh_;                                                \
      const float sc_ = __int_as_float((127 + sh_) << 23);                          \
      x1 *= sc_; x2 *= sc_; areg *= sc_; E -= sh_;                                  \
    }                                                                               \
    __syncthreads();                                                                \
} while (0)

__global__ __launch_bounds__(256, 1) void sdtw_kernel(const float* __restrict__ D,
                                                      float* __restrict__ out) {
  static_assert(NCHUNK % 2 == 0, "loop is 2x unrolled");
  __shared__ float bnd[NWAVE + 1][BROW];  // [4] = dump row for wave 3
  __shared__ int bndE[NWAVE][36];         // per-wave per-chunk lane-63 scale E
  const int tid = threadIdx.x;
  const int w = tid >> 6, l = tid & 63, b = blockIdx.x;

  u32x4 srd;  // raw buffer descriptor over D: OOB reads return 0, never fault
  const uint64_t base = (uint64_t)(const void*)D;
  srd[0] = (unsigned)base;
  srd[1] = (unsigned)(base >> 32) & 0xffffu;  // stride=0
  srd[2] = 64u * 512u * 512u * 4u;            // num_records (bytes)
  srd[3] = 0x00020000u;

  const int r1 = (w << 7) + (l << 1);       // D row of i1 (0-based)
  const int byte1 = ((b << 9) + r1) << 11;  // (b*512 + r1) * 512 * 4
  const int ow = w * DELTA;
  const bool isL0 = (l == 0);

  float* __restrict__ bwr = &bnd[(w == NWAVE - 1) ? NWAVE : w][0];
  float* __restrict__ brd = &bnd[(w == 0) ? 0 : (w - 1)][0];
  int* __restrict__ bwrE = &bndE[w][0];
  int* __restrict__ brdE = &bndE[(w == 0) ? 0 : (w - 1)][0];

  float x1 = 0.0f, x2 = 0.0f, areg = 0.0f;  // P(INF) = 0
  int E = 0;                                // per-lane scale exponent

  // D double-buffers as NAMED registers (arrays were lowered to scratch)
  f4 qa0, qa1, qa2, qa3, qa4, qa5, qa6;
  f4 qb0, qb1, qb2, qb3, qb4, qb5, qb6;
  float ea0, ea1, ea2, ea3, eb0, eb1, eb2, eb3;

  ISSUE(qa0, qa1, qa2, qa3, qa4, qa5, qa6, ea0, ea1, ea2, ea3, -ow);  // chunk 0
  for (int mc = 0; mc < NCHUNK; mc += 2) {
    BODY(qa0, qa1, qa2, qa3, qa4, qa5, qa6, ea0, ea1, ea2, ea3,
         qb0, qb1, qb2, qb3, qb4, qb5, qb6, eb0, eb1, eb2, eb3, mc);
    BODY(qb0, qb1, qb2, qb3, qb4, qb5, qb6, eb0, eb1, eb2, eb3,
         qa0, qa1, qa2, qa3, qa4, qa5, qa6, ea0, ea1, ea2, ea3, mc + 1);
  }

  if (tid == NWAVE * 64 - 1) {
    // x2 * 2^E = exp(-R[512][512]);  v_log_f32 is log2
    const float Rv = -(__builtin_amdgcn_logf(x2) + (float)E);
    out[b] = Rv * LN2;
  }
}

extern "C" void kernel_launch(void* const* d_in, const int* in_sizes, int n_in,
                              void* d_out, int out_size, void* d_ws, size_t ws_size,
                              hipStream_t stream) {
  const float* D = (const float*)d_in[0];
  float* out = (float*)d_out;
  hipLaunchKernelGGL(sdtw_kernel, dim3(64), dim3(NWAVE * 64), 0, stream, D, out);
}